// Round 8
// baseline (1200.479 us; speedup 1.0000x reference)
//
#include <hip/hip_runtime.h>

// PWC-Net cost volume, fp32. B=4, C=128, H=256, W=448, 81 shifts.
// out[b, di*9+dj, h, w] = (1/128) * sum_c feat1[b,c,h,w] * feat2[b,c,h+di-4,w+dj-4]
//
// Block = (b,h), 512 thr / 8 waves. Lane item it = tid: di = it/56,
// px0 = (it%56)*8 (504 real). Per channel, one LDS buffer of 10 rows x 114
// 16B-atoms: rows 0..8 = feat2 rows h-4..h+4, row 9 = feat1 row h. Atom a
// covers cols 4a-4..4a-1; slot permutation tau(2x)=x, tau(2x+1)=57+x makes
// every window read (atoms 2m+k, consecutive m across lanes) hit each LDS
// bank-group exactly 2x per 16-lane quarter -> conflict-free. Halo atoms
// 0/113 land on slots 0/113 (zeroed once, never staged). Stage = 20
// global_load_lds(16B) issues/channel (wid<4: 3, else 2), linear LDS dest,
// tau-inverse applied on the global source address. OOB rows -> LDS trash.
//
// Pipeline: ring of 4 buffers, stage distance 3. Per body t:
//   s_waitcnt vmcnt(2*nIss)  <- drains ONLY bundle t (issued 3 iters ago,
//                               ~2500 cy of cover for loaded HBM/L2 latency)
//   s_barrier                <- pure join: publishes buf t, protects buf t&3
//                               (overwritten by stage issued at body t+1)
//   issue bundle t+3 (never drained young)
//   6x ds_read_b128 + 72 FMA

typedef __attribute__((ext_vector_type(4))) float f32x4;

#define GLAS(p) ((const __attribute__((address_space(1))) unsigned int*)(p))
#define LDAS(p) ((__attribute__((address_space(3))) unsigned int*)(p))

#define WAIT_MAIN() do { if (wid < 4) asm volatile("s_waitcnt vmcnt(6)" ::: "memory"); \
                         else         asm volatile("s_waitcnt vmcnt(4)" ::: "memory"); } while (0)
#define WAIT_ONE()  do { if (wid < 4) asm volatile("s_waitcnt vmcnt(3)" ::: "memory"); \
                         else         asm volatile("s_waitcnt vmcnt(2)" ::: "memory"); } while (0)
#define WAIT_ZERO() asm volatile("s_waitcnt vmcnt(0)" ::: "memory")

__global__ __launch_bounds__(512, 4) void cv_kernel(
    const float* __restrict__ feat1,
    const float* __restrict__ feat2,
    float* __restrict__ out)
{
    constexpr int C = 128, H = 256, W = 448;
    constexpr size_t HW = (size_t)H * W;
    constexpr int ROWB  = 114 * 16;     // 1824 B per row (114 slots)
    constexpr int BUFB  = 10 * ROWB;    // 18240 B per ring buffer
    constexpr int TRASH = 4 * BUFB;     // 896 B trash row for OOB stage
    __shared__ __align__(16) char f2s[4 * BUFB + 896];   // 73856 B

    const int tid  = threadIdx.x;
    const int wid  = tid >> 6;
    const int lane = tid & 63;

    // XCD-contiguous (b,h) mapping (1024 = 8*128, bijective)
    const int lin = (blockIdx.x & 7) * 128 + (blockIdx.x >> 3);
    const int b = lin >> 8, h = lin & 255;

    const int it  = (tid < 504) ? tid : 503;
    const int di  = it / 56;
    const int m   = it - di * 56;
    const int px0 = m << 3;

    // Zero all LDS once: halo slots 0/113 + OOB rows stay zero forever.
    for (int i = tid; i < (int)sizeof(f2s) / 16; i += 512)
        *(f32x4*)(f2s + i * 16) = (f32x4){0.f, 0.f, 0.f, 0.f};

    // ---- staging descriptors: 20 issues j = 2r+cc, r=0..9 (r<9: feat2 row
    // h+r-4; r==9: feat1 row h), cc = half. Dest slots 1+56cc .. 56+56cc hold
    // atoms 2l+2 (cc=0) / 2l+1 (cc=1)  -> source float col 8l+4*(cc^1).
    // Wave wid: j = wid, wid+8, (16+wid if wid<4).  nIss = 3 (wid<4) else 2.
    const int nIss = (wid < 4) ? 3 : 2;
    const float* sp[3]; int sdst[3]; bool srv[3];
#pragma unroll
    for (int k = 0; k < 3; ++k) {
        if (k < nIss) {
            const int j  = (k < 2) ? (wid + 8 * k) : (16 + wid);
            const int r  = j >> 1, cc = j & 1;
            const int colof = 8 * lane + 4 * (cc ^ 1);
            if (r == 9) {
                srv[k] = true;
                sp[k]  = feat1 + ((size_t)b * C * H + (size_t)h) * W + colof;
            } else {
                const int hr = h + r - 4;
                srv[k] = (hr >= 0) && (hr < H);
                sp[k]  = feat2 + ((size_t)b * C * H + (size_t)(srv[k] ? hr : 0)) * W + colof;
            }
            sdst[k] = r * ROWB + 16 + cc * 896;
        }
    }

    // ---- read offsets. Window atoms 2m..2m+3 -> slots m, 57+m, m+1, 58+m
    // (row di). feat1 atoms 2m+1, 2m+2 -> slots 57+m, m+1 (row 9).
    const int lofs0 = di * ROWB + m * 16;
    const int lofs1 = di * ROWB + (57 + m) * 16;
    const int lofs2 = di * ROWB + (m + 1) * 16;
    const int lofs3 = di * ROWB + (58 + m) * 16;
    const int fofs0 = 9 * ROWB + (57 + m) * 16;
    const int fofs1 = 9 * ROWB + (m + 1) * 16;

    float acc[9][8];
#pragma unroll
    for (int j = 0; j < 9; ++j)
#pragma unroll
        for (int p = 0; p < 8; ++p) acc[j][p] = 0.0f;

    __syncthreads();   // LDS zeros visible before any stage lands

#define STAGE(NS) do { \
    _Pragma("unroll") \
    for (int k = 0; k < 3; ++k) { \
        if (k < nIss) { \
            char* dst = srv[k] ? (f2s + (NS) * BUFB + sdst[k]) : (f2s + TRASH); \
            if (lane < 56) \
                __builtin_amdgcn_global_load_lds(GLAS(sp[k]), LDAS(dst), 16, 0, 0); \
            sp[k] += HW; \
        } \
    } } while (0)

#define COMPUTE(S) do { \
    const char* lb = f2s + (S) * BUFB; \
    const f32x4 w0 = *(const f32x4*)(lb + lofs0); \
    const f32x4 w1 = *(const f32x4*)(lb + lofs1); \
    const f32x4 w2 = *(const f32x4*)(lb + lofs2); \
    const f32x4 w3 = *(const f32x4*)(lb + lofs3); \
    const f32x4 x0 = *(const f32x4*)(lb + fofs0); \
    const f32x4 x1 = *(const f32x4*)(lb + fofs1); \
    const float a[8]  = {x0.x, x0.y, x0.z, x0.w, x1.x, x1.y, x1.z, x1.w}; \
    const float w[16] = {w0.x, w0.y, w0.z, w0.w, w1.x, w1.y, w1.z, w1.w, \
                         w2.x, w2.y, w2.z, w2.w, w3.x, w3.y, w3.z, w3.w}; \
    _Pragma("unroll") \
    for (int dj = 0; dj < 9; ++dj) { \
        _Pragma("unroll") \
        for (int p = 0; p < 8; ++p) \
            acc[dj][p] = fmaf(a[p], w[dj + p], acc[dj][p]); \
    } } while (0)

#define BODY(S, NS, MODE) do { \
    if ((MODE) <= 1) WAIT_MAIN(); \
    else if ((MODE) == 2) WAIT_ONE(); \
    else WAIT_ZERO(); \
    __builtin_amdgcn_s_barrier(); \
    __builtin_amdgcn_sched_barrier(0); \
    if ((MODE) == 0) STAGE(NS); \
    COMPUTE(S); \
  } while (0)

    // Prologue: bundles 0,1,2 into ring slots 0,1,2.
    STAGE(0); STAGE(1); STAGE(2);

    // Bodies t = 0..123 (31 x 4, all main-mode), then tail 124..127.
    for (int t = 0; t < 124; t += 4) {
        BODY(0, 3, 0); BODY(1, 0, 0); BODY(2, 1, 0); BODY(3, 2, 0);
    }
    BODY(0, 3, 0);   // t=124: issues bundle 127
    BODY(1, 0, 1);   // t=125: wait main (2 bundles left)
    BODY(2, 1, 2);   // t=126: wait 1 bundle
    BODY(3, 2, 3);   // t=127: wait 0

    if (tid < 504) {
        const float s = 1.0f / 128.0f;
        float* ob = out + (((size_t)(b * 81 + di * 9)) * H + h) * W + px0;
#pragma unroll
        for (int dj = 0; dj < 9; ++dj) {
            f32x4 o0, o1;
            o0.x = acc[dj][0] * s; o0.y = acc[dj][1] * s;
            o0.z = acc[dj][2] * s; o0.w = acc[dj][3] * s;
            o1.x = acc[dj][4] * s; o1.y = acc[dj][5] * s;
            o1.z = acc[dj][6] * s; o1.w = acc[dj][7] * s;
            float* op = ob + (size_t)dj * HW;
            *(f32x4*)(op)     = o0;
            *(f32x4*)(op + 4) = o1;
        }
    }
}

extern "C" void kernel_launch(void* const* d_in, const int* in_sizes, int n_in,
                              void* d_out, int out_size, void* d_ws, size_t ws_size,
                              hipStream_t stream) {
    const float* feat1 = (const float*)d_in[0];
    const float* feat2 = (const float*)d_in[1];
    float* out = (float*)d_out;
    cv_kernel<<<dim3(1024), dim3(512), 0, stream>>>(feat1, feat2, out);
}

// Round 9
// 299.880 us; speedup vs baseline: 4.0032x; 4.0032x over previous
//
#include <hip/hip_runtime.h>

// PWC-Net cost volume, fp32. B=4, C=128, H=256, W=448, 81 shifts.
// out[b, di*9+dj, h, w] = (1/128) * sum_c feat1[b,c,h,w] * feat2[b,c,h+di-4,w+dj-4]
//
// Barrier-free, LDS-staging-free. One wave per (b,h,di) (9216 waves). Lane
// owns 8 px (m = lane, 56 active). Per channel each lane loads ONLY its own
// 8 feat1 + 8 feat2 floats (4x b128, fully coalesced, zero overlap between
// lanes). The 16-float window = left4 | own8 | right4, where left4 = lane
// m-1's upper feat2 quad and right4 = lane m+1's lower quad, fetched with 8
// ds_bpermute_b32 (LDS crossbar; no LDS memory, no barriers). Horizontal
// edges: lanes m=0 / m=55 accumulate neighbor garbage only into acc slots
// whose output is defined 0 (col<0 / col>447) -> zeroed in the epilogue.
// Vertical OOB rows are wave-uniform -> store zeros, exit. feat1/feat2
// register-prefetched one channel ahead.

typedef __attribute__((ext_vector_type(4))) float f32x4;

__device__ __forceinline__ float bperm(int idx, float v) {
    return __int_as_float(__builtin_amdgcn_ds_bpermute(idx, __float_as_int(v)));
}

__global__ __launch_bounds__(256, 4) void cv_kernel(
    const float* __restrict__ feat1,
    const float* __restrict__ feat2,
    float* __restrict__ out)
{
    constexpr int C = 128, H = 256, W = 448;
    constexpr unsigned HW = (unsigned)(H * W);

    const int tid  = threadIdx.x;
    const int wid  = tid >> 6;
    const int lane = tid & 63;

    // 2304 blocks = 8 * 288: XCD-contiguous item mapping (bijective).
    const int swz  = (blockIdx.x & 7) * 288 + (blockIdx.x >> 3);
    const int item = swz * 4 + wid;          // 0..9215
    const int di   = item % 9;
    const int bh   = item / 9;
    const int h    = bh & 255;
    const int b    = bh >> 8;

    const int m   = (lane < 56) ? lane : 55;
    const int px0 = m << 3;
    const int hr  = h + di - 4;

    float* ob = out + (((size_t)(b * 81 + di * 9)) * H + h) * W + px0;

    if (hr < 0 || hr >= H) {                 // wave-uniform: whole row zero
        if (lane < 56) {
            const f32x4 z = {0.f, 0.f, 0.f, 0.f};
#pragma unroll
            for (int dj = 0; dj < 9; ++dj) {
                *(f32x4*)(ob + (size_t)dj * HW)     = z;
                *(f32x4*)(ob + (size_t)dj * HW + 4) = z;
            }
        }
        return;
    }

    unsigned f1o = (unsigned)(((b * C * H) + h) * W + px0);   // float index
    unsigned f2o = (unsigned)(((b * C * H) + hr) * W + px0);

    const int idxL = ((lane - 1) & 63) << 2;  // pull from lane m-1
    const int idxR = ((lane + 1) & 63) << 2;  // pull from lane m+1

    float acc[9][8];
#pragma unroll
    for (int j = 0; j < 9; ++j)
#pragma unroll
        for (int p = 0; p < 8; ++p) acc[j][p] = 0.0f;

    // Prefetch channel 0.
    f32x4 ca0 = *(const f32x4*)(feat1 + f1o);
    f32x4 ca1 = *(const f32x4*)(feat1 + f1o + 4);
    f32x4 cb0 = *(const f32x4*)(feat2 + f2o);
    f32x4 cb1 = *(const f32x4*)(feat2 + f2o + 4);
    f1o += HW; f2o += HW;

    for (int t = 0; t < C - 1; ++t) {
        // Issue next channel's loads (consumed next iteration).
        const f32x4 na0 = *(const f32x4*)(feat1 + f1o);
        const f32x4 na1 = *(const f32x4*)(feat1 + f1o + 4);
        const f32x4 nb0 = *(const f32x4*)(feat2 + f2o);
        const f32x4 nb1 = *(const f32x4*)(feat2 + f2o + 4);
        f1o += HW; f2o += HW;

        // Window via crossbar: left4 = (m-1).cb1, right4 = (m+1).cb0.
        const float w[16] = {
            bperm(idxL, cb1.x), bperm(idxL, cb1.y), bperm(idxL, cb1.z), bperm(idxL, cb1.w),
            cb0.x, cb0.y, cb0.z, cb0.w, cb1.x, cb1.y, cb1.z, cb1.w,
            bperm(idxR, cb0.x), bperm(idxR, cb0.y), bperm(idxR, cb0.z), bperm(idxR, cb0.w)};
        const float a[8] = {ca0.x, ca0.y, ca0.z, ca0.w, ca1.x, ca1.y, ca1.z, ca1.w};
#pragma unroll
        for (int dj = 0; dj < 9; ++dj)
#pragma unroll
            for (int p = 0; p < 8; ++p)
                acc[dj][p] = fmaf(a[p], w[dj + p], acc[dj][p]);

        ca0 = na0; ca1 = na1; cb0 = nb0; cb1 = nb1;
    }
    {   // Last channel (no prefetch).
        const float w[16] = {
            bperm(idxL, cb1.x), bperm(idxL, cb1.y), bperm(idxL, cb1.z), bperm(idxL, cb1.w),
            cb0.x, cb0.y, cb0.z, cb0.w, cb1.x, cb1.y, cb1.z, cb1.w,
            bperm(idxR, cb0.x), bperm(idxR, cb0.y), bperm(idxR, cb0.z), bperm(idxR, cb0.w)};
        const float a[8] = {ca0.x, ca0.y, ca0.z, ca0.w, ca1.x, ca1.y, ca1.z, ca1.w};
#pragma unroll
        for (int dj = 0; dj < 9; ++dj)
#pragma unroll
            for (int p = 0; p < 8; ++p)
                acc[dj][p] = fmaf(a[p], w[dj + p], acc[dj][p]);
    }

    if (lane < 56) {
        const float s = 1.0f / 128.0f;
#pragma unroll
        for (int dj = 0; dj < 9; ++dj) {
            float o[8];
#pragma unroll
            for (int p = 0; p < 8; ++p) {
                float v = acc[dj][p] * s;
                // out col = px0 + p + dj - 4: zero where col<0 (m==0, p+dj<4)
                // or col>447 (m==55, p+dj>11) — garbage-fed slots.
                if (dj + p < 4)  v = (m == 0)  ? 0.f : v;
                if (dj + p > 11) v = (m == 55) ? 0.f : v;
                o[p] = v;
            }
            f32x4 o0 = {o[0], o[1], o[2], o[3]};
            f32x4 o1 = {o[4], o[5], o[6], o[7]};
            *(f32x4*)(ob + (size_t)dj * HW)     = o0;
            *(f32x4*)(ob + (size_t)dj * HW + 4) = o1;
        }
    }
}

extern "C" void kernel_launch(void* const* d_in, const int* in_sizes, int n_in,
                              void* d_out, int out_size, void* d_ws, size_t ws_size,
                              hipStream_t stream) {
    const float* feat1 = (const float*)d_in[0];
    const float* feat2 = (const float*)d_in[1];
    float* out = (float*)d_out;
    cv_kernel<<<dim3(2304), dim3(256), 0, stream>>>(feat1, feat2, out);
}